// Round 5
// baseline (821.539 us; speedup 1.0000x reference)
//
#include <hip/hip_runtime.h>
#include <hip/hip_bf16.h>
#include <math.h>

#define SEQ 2048
#define DIM 2048
#define NHEAD 16
#define HD 128
#define HIDDEN 5632
#define QKVN 6144
#define NCHUNK_TOT 80   // sum_{it=0}^{31} (it/8 + 1)
constexpr float EPS = 1e-6f;

typedef __hip_bfloat16 bf16;
using short8  = __attribute__((ext_vector_type(8))) short;
using short4v = __attribute__((ext_vector_type(4))) short;
using floatx4 = __attribute__((ext_vector_type(4))) float;

__device__ inline void gl_lds16(const void* g, void* l) {
    __builtin_amdgcn_global_load_lds((const __attribute__((address_space(1))) void*)g,
                                     (__attribute__((address_space(3))) void*)l, 16, 0, 0);
}

__device__ inline short bfbits(float f) {
    bf16 b = __float2bfloat16(f);
    return *(const short*)&b;
}

// ---------------------------------------------------------------- rmsnorm (f32 in, bf16 out)
__global__ __launch_bounds__(256) void rmsnorm_kernel(const float* __restrict__ x,
                                                      const float* __restrict__ g,
                                                      bf16* __restrict__ out) {
    int row = blockIdx.x;
    const float4* xr = (const float4*)(x + (size_t)row * DIM);
    const float4* g4 = (const float4*)g;
    float4 v[2];
    float ss = 0.f;
#pragma unroll
    for (int i = 0; i < 2; ++i) {
        v[i] = xr[threadIdx.x + 256 * i];
        ss += v[i].x * v[i].x + v[i].y * v[i].y + v[i].z * v[i].z + v[i].w * v[i].w;
    }
    __shared__ float red[256];
    red[threadIdx.x] = ss;
    __syncthreads();
    for (int s = 128; s > 0; s >>= 1) {
        if (threadIdx.x < s) red[threadIdx.x] += red[threadIdx.x + s];
        __syncthreads();
    }
    float scale = rsqrtf(red[0] / (float)DIM + EPS);
    bf16* orow = out + (size_t)row * DIM;
#pragma unroll
    for (int i = 0; i < 2; ++i) {
        float4 gv = g4[threadIdx.x + 256 * i];
        short4v o;
        o[0] = bfbits(v[i].x * scale * gv.x);
        o[1] = bfbits(v[i].y * scale * gv.y);
        o[2] = bfbits(v[i].z * scale * gv.z);
        o[3] = bfbits(v[i].w * scale * gv.w);
        *(short4v*)&orow[(threadIdx.x + 256 * i) * 4] = o;
    }
}

// ---------------------------------------------------------------- weight cast+transpose
__global__ __launch_bounds__(256) void cvt_t_kernel(const float* __restrict__ in,
                                                    bf16* __restrict__ out,
                                                    int K, int N) {
    __shared__ bf16 L[64][72];
    const int nb = blockIdx.x * 64, kb = blockIdx.y * 64;
    const int t = threadIdx.x;
    const int nq = t & 15;   // n group of 4
    const int kq = t >> 4;   // k group of 4
    float4 v[4];
#pragma unroll
    for (int i = 0; i < 4; ++i)
        v[i] = *(const float4*)&in[(size_t)(kb + kq * 4 + i) * N + nb + nq * 4];
#pragma unroll
    for (int j = 0; j < 4; ++j) {
        short4v o;
#pragma unroll
        for (int i = 0; i < 4; ++i)
            o[i] = bfbits(((const float*)&v[i])[j]);
        *(short4v*)&L[nq * 4 + j][kq * 4] = o;
    }
    __syncthreads();
    const int c8 = t & 7, rw = t >> 3;
#pragma unroll
    for (int p = 0; p < 2; ++p) {
        int row = rw + p * 32;
        *(short8*)&out[(size_t)(nb + row) * K + kb + c8 * 8] = *(const short8*)&L[row][c8 * 8];
    }
}

// ---------------------------------------------------------------- bf16 MFMA GEMM (128x128, 2-phase)
template <int MODE>
__global__ __launch_bounds__(256) void gemm_bf16(const bf16* __restrict__ A,
                                                 const bf16* __restrict__ Bt,
                                                 void* __restrict__ Cv,
                                                 const float* __restrict__ R,
                                                 int K, int ldc) {
    __shared__ bf16 Asm[2][128 * 32];
    __shared__ bf16 Bsm[2][128 * 32];
    const int t = threadIdx.x;

    int wg = blockIdx.y * gridDim.x + blockIdx.x;
    {
        const int nwg = gridDim.x * gridDim.y;
        const int q = nwg >> 3, r = nwg & 7;
        const int xcd = wg & 7, loc = wg >> 3;
        wg = (xcd < r ? xcd * (q + 1) : r * (q + 1) + (xcd - r) * q) + loc;
    }
    const int m0 = (wg / gridDim.x) * 128;
    const int n0 = (wg % gridDim.x) * 128;

    const int lane = t & 63;
    const int wave = t >> 6;
    const int wr = wave >> 1, wc = wave & 1;
    const int quad = lane >> 4;
    const int l16 = lane & 15;

    floatx4 acc[4][4] = {};

    const int ar = t >> 2;
    const int ak = (t & 3) * 8;
    const bf16* Ag = A + (size_t)(m0 + ar) * K + ak;
    const bf16* Bg = Bt + (size_t)(n0 + ar) * K + ak;
    const size_t half = (size_t)64 * K;

    gl_lds16(Ag, Asm[0] + t * 8);
    gl_lds16(Ag + half, Asm[0] + t * 8 + 64 * 32);
    gl_lds16(Bg, Bsm[0] + t * 8);
    gl_lds16(Bg + half, Bsm[0] + t * 8 + 64 * 32);
    __syncthreads();

    int cur = 0;
    for (int k0 = 0; k0 < K; k0 += 32) {
        if (k0 + 32 < K) {
            const int nb = cur ^ 1;
            gl_lds16(Ag + k0 + 32, Asm[nb] + t * 8);
            gl_lds16(Ag + k0 + 32 + half, Asm[nb] + t * 8 + 64 * 32);
            gl_lds16(Bg + k0 + 32, Bsm[nb] + t * 8);
            gl_lds16(Bg + k0 + 32 + half, Bsm[nb] + t * 8 + 64 * 32);
        }

        const bf16* As = Asm[cur];
        const bf16* Bs = Bsm[cur];
        short8 af[4], bfr[4];
#pragma unroll
        for (int i = 0; i < 4; ++i)
            af[i] = *(const short8*)(As + (wr * 64 + i * 16 + l16) * 32 + quad * 8);
#pragma unroll
        for (int j = 0; j < 4; ++j)
            bfr[j] = *(const short8*)(Bs + (wc * 64 + j * 16 + l16) * 32 + quad * 8);
#pragma unroll
        for (int i = 0; i < 4; ++i)
#pragma unroll
            for (int j = 0; j < 4; ++j)
                acc[i][j] = __builtin_amdgcn_mfma_f32_16x16x32_bf16(af[i], bfr[j], acc[i][j], 0, 0, 0);

        __syncthreads();
        cur ^= 1;
    }

#pragma unroll
    for (int i = 0; i < 4; ++i) {
#pragma unroll
        for (int j = 0; j < 4; ++j) {
#pragma unroll
            for (int r = 0; r < 4; ++r) {
                int m = m0 + wr * 64 + i * 16 + quad * 4 + r;
                int n = n0 + wc * 64 + j * 16 + l16;
                size_t idx = (size_t)m * ldc + n;
                float v = acc[i][j][r];
                if (MODE == 0) {
                    ((bf16*)Cv)[idx] = __float2bfloat16(v);
                } else {
                    ((float*)Cv)[idx] = v + R[idx];
                }
            }
        }
    }
}

// ---------------------------------------------------------------- wide GEMM (128x256, 2-phase)
// Same skeleton as gemm_w13 (proven): A staged ONCE per K-step, two 128-col
// B panels from ONE weight matrix -> 32 MFMA/wave per 24KB staged (2x the
// intensity of the 128x128 kernel; that ratio measured 610 vs 400 TF).
// kbase/klen support split-K (partials as raw f32, MODE 4).
template <int MODE>
__global__ __launch_bounds__(256, 2) void gemm_wide(const bf16* __restrict__ A,
                                                    const bf16* __restrict__ Bt,
                                                    void* __restrict__ Cv,
                                                    int ldk, int kbase, int klen,
                                                    int ldc) {
    __shared__ bf16 Asm[2][128 * 32];
    __shared__ bf16 B1s[2][128 * 32];
    __shared__ bf16 B3s[2][128 * 32];
    const int t = threadIdx.x;

    int wg = blockIdx.y * gridDim.x + blockIdx.x;
    {
        const int nwg = gridDim.x * gridDim.y;
        const int q = nwg >> 3, r = nwg & 7;
        const int xcd = wg & 7, loc = wg >> 3;
        wg = (xcd < r ? xcd * (q + 1) : r * (q + 1) + (xcd - r) * q) + loc;
    }
    const int m0 = (wg / gridDim.x) * 128;
    const int n0 = (wg % gridDim.x) * 256;

    const int lane = t & 63;
    const int wave = t >> 6;
    const int wr = wave >> 1, wc = wave & 1;
    const int quad = lane >> 4;
    const int l16 = lane & 15;

    floatx4 acc1[4][4] = {};
    floatx4 acc3[4][4] = {};

    const int ar = t >> 2;
    const int ak = (t & 3) * 8;
    const bf16* Ag  = A  + (size_t)(m0 + ar) * ldk + kbase + ak;
    const bf16* B1g = Bt + (size_t)(n0 + ar) * ldk + kbase + ak;
    const bf16* B3g = Bt + (size_t)(n0 + 128 + ar) * ldk + kbase + ak;
    const size_t half = (size_t)64 * ldk;

    auto stage = [&](int k, int buf) {
        gl_lds16(Ag + k, Asm[buf] + t * 8);
        gl_lds16(Ag + k + half, Asm[buf] + t * 8 + 64 * 32);
        gl_lds16(B1g + k, B1s[buf] + t * 8);
        gl_lds16(B1g + k + half, B1s[buf] + t * 8 + 64 * 32);
        gl_lds16(B3g + k, B3s[buf] + t * 8);
        gl_lds16(B3g + k + half, B3s[buf] + t * 8 + 64 * 32);
    };

    stage(0, 0);
    __syncthreads();

    int cur = 0;
    for (int k0 = 0; k0 < klen; k0 += 32) {
        if (k0 + 32 < klen) stage(k0 + 32, cur ^ 1);

        const bf16* As = Asm[cur];
        short8 af[4], bfr[4];
#pragma unroll
        for (int i = 0; i < 4; ++i)
            af[i] = *(const short8*)(As + (wr * 64 + i * 16 + l16) * 32 + quad * 8);

        const bf16* B1 = B1s[cur];
#pragma unroll
        for (int j = 0; j < 4; ++j)
            bfr[j] = *(const short8*)(B1 + (wc * 64 + j * 16 + l16) * 32 + quad * 8);
#pragma unroll
        for (int i = 0; i < 4; ++i)
#pragma unroll
            for (int j = 0; j < 4; ++j)
                acc1[i][j] = __builtin_amdgcn_mfma_f32_16x16x32_bf16(af[i], bfr[j], acc1[i][j], 0, 0, 0);

        const bf16* B3 = B3s[cur];
#pragma unroll
        for (int j = 0; j < 4; ++j)
            bfr[j] = *(const short8*)(B3 + (wc * 64 + j * 16 + l16) * 32 + quad * 8);
#pragma unroll
        for (int i = 0; i < 4; ++i)
#pragma unroll
            for (int j = 0; j < 4; ++j)
                acc3[i][j] = __builtin_amdgcn_mfma_f32_16x16x32_bf16(af[i], bfr[j], acc3[i][j], 0, 0, 0);

        __syncthreads();
        cur ^= 1;
    }

#pragma unroll
    for (int i = 0; i < 4; ++i) {
#pragma unroll
        for (int j = 0; j < 4; ++j) {
#pragma unroll
            for (int r = 0; r < 4; ++r) {
                int m = m0 + wr * 64 + i * 16 + quad * 4 + r;
                int n = n0 + wc * 64 + j * 16 + l16;
                float v1 = acc1[i][j][r];
                float v3 = acc3[i][j][r];
                if (MODE == 0) {
                    ((bf16*)Cv)[(size_t)m * ldc + n]       = __float2bfloat16(v1);
                    ((bf16*)Cv)[(size_t)m * ldc + n + 128] = __float2bfloat16(v3);
                } else {   // MODE 4: raw f32 partials (split-K)
                    ((float*)Cv)[(size_t)m * ldc + n]       = v1;
                    ((float*)Cv)[(size_t)m * ldc + n + 128] = v3;
                }
            }
        }
    }
}

// ---------------------------------------------------------------- fused W1/W3 SwiGLU GEMM
__global__ __launch_bounds__(256, 2) void gemm_w13(const bf16* __restrict__ A,
                                                   const bf16* __restrict__ B1t,
                                                   const bf16* __restrict__ B3t,
                                                   bf16* __restrict__ C,
                                                   int K, int ldc) {
    __shared__ bf16 Asm[2][128 * 32];
    __shared__ bf16 B1s[2][128 * 32];
    __shared__ bf16 B3s[2][128 * 32];
    const int t = threadIdx.x;

    int wg = blockIdx.y * gridDim.x + blockIdx.x;
    {
        const int nwg = gridDim.x * gridDim.y;
        const int q = nwg >> 3, r = nwg & 7;
        const int xcd = wg & 7, loc = wg >> 3;
        wg = (xcd < r ? xcd * (q + 1) : r * (q + 1) + (xcd - r) * q) + loc;
    }
    const int m0 = (wg / gridDim.x) * 128;
    const int n0 = (wg % gridDim.x) * 128;

    const int lane = t & 63;
    const int wave = t >> 6;
    const int wr = wave >> 1, wc = wave & 1;
    const int quad = lane >> 4;
    const int l16 = lane & 15;

    floatx4 acc1[4][4] = {};
    floatx4 acc3[4][4] = {};

    const int ar = t >> 2;
    const int ak = (t & 3) * 8;
    const bf16* Ag  = A   + (size_t)(m0 + ar) * K + ak;
    const bf16* B1g = B1t + (size_t)(n0 + ar) * K + ak;
    const bf16* B3g = B3t + (size_t)(n0 + ar) * K + ak;
    const size_t half = (size_t)64 * K;

    auto stage = [&](int k, int buf) {
        gl_lds16(Ag + k, Asm[buf] + t * 8);
        gl_lds16(Ag + k + half, Asm[buf] + t * 8 + 64 * 32);
        gl_lds16(B1g + k, B1s[buf] + t * 8);
        gl_lds16(B1g + k + half, B1s[buf] + t * 8 + 64 * 32);
        gl_lds16(B3g + k, B3s[buf] + t * 8);
        gl_lds16(B3g + k + half, B3s[buf] + t * 8 + 64 * 32);
    };

    stage(0, 0);
    __syncthreads();

    int cur = 0;
    for (int k0 = 0; k0 < K; k0 += 32) {
        if (k0 + 32 < K) stage(k0 + 32, cur ^ 1);

        const bf16* As = Asm[cur];
        short8 af[4], bfr[4];
#pragma unroll
        for (int i = 0; i < 4; ++i)
            af[i] = *(const short8*)(As + (wr * 64 + i * 16 + l16) * 32 + quad * 8);

        const bf16* B1 = B1s[cur];
#pragma unroll
        for (int j = 0; j < 4; ++j)
            bfr[j] = *(const short8*)(B1 + (wc * 64 + j * 16 + l16) * 32 + quad * 8);
#pragma unroll
        for (int i = 0; i < 4; ++i)
#pragma unroll
            for (int j = 0; j < 4; ++j)
                acc1[i][j] = __builtin_amdgcn_mfma_f32_16x16x32_bf16(af[i], bfr[j], acc1[i][j], 0, 0, 0);

        const bf16* B3 = B3s[cur];
#pragma unroll
        for (int j = 0; j < 4; ++j)
            bfr[j] = *(const short8*)(B3 + (wc * 64 + j * 16 + l16) * 32 + quad * 8);
#pragma unroll
        for (int i = 0; i < 4; ++i)
#pragma unroll
            for (int j = 0; j < 4; ++j)
                acc3[i][j] = __builtin_amdgcn_mfma_f32_16x16x32_bf16(af[i], bfr[j], acc3[i][j], 0, 0, 0);

        __syncthreads();
        cur ^= 1;
    }

#pragma unroll
    for (int i = 0; i < 4; ++i) {
#pragma unroll
        for (int j = 0; j < 4; ++j) {
#pragma unroll
            for (int r = 0; r < 4; ++r) {
                int m = m0 + wr * 64 + i * 16 + quad * 4 + r;
                int n = n0 + wc * 64 + j * 16 + l16;
                float v1 = acc1[i][j][r];
                float v3 = acc3[i][j][r];
                float s = v1 / (1.f + __expf(-v1));
                C[(size_t)m * ldc + n] = __float2bfloat16(s * v3);
            }
        }
    }
}

// ---------------------------------------------------------------- split-K combine: out = p0+p1+h
__global__ __launch_bounds__(256) void combine2(const float* __restrict__ p0,
                                                const float* __restrict__ p1,
                                                const float* __restrict__ h,
                                                float* __restrict__ out) {
    size_t i = ((size_t)blockIdx.x * 256 + threadIdx.x) * 4;
    float4 a = *(const float4*)&p0[i];
    float4 b = *(const float4*)&p1[i];
    float4 c = *(const float4*)&h[i];
    float4 o;
    o.x = a.x + b.x + c.x;
    o.y = a.y + b.y + c.y;
    o.z = a.z + b.z + c.z;
    o.w = a.w + b.w + c.w;
    *(float4*)&out[i] = o;
}

// ---------------------------------------------------------------- RoPE (in-place, bf16 qkv buffer)
__global__ __launch_bounds__(256) void rope_kernel(bf16* __restrict__ qkv,
                                                   const float* __restrict__ cs,
                                                   const float* __restrict__ sn) {
    int idx = blockIdx.x * 256 + threadIdx.x;
    int d2 = idx % (HD / 2);
    int rest = idx / (HD / 2);
    int h = rest % NHEAD;
    int s = rest / NHEAD;
    float c = cs[s * (HD / 2) + d2];
    float si = sn[s * (HD / 2) + d2];
    bf16* qp = qkv + (size_t)s * QKVN + h * HD + 2 * d2;
    bf16* kp = qp + DIM;
    float qr = __bfloat162float(qp[0]), qi = __bfloat162float(qp[1]);
    qp[0] = __float2bfloat16(qr * c - qi * si);
    qp[1] = __float2bfloat16(qr * si + qi * c);
    float kr = __bfloat162float(kp[0]), ki = __bfloat162float(kp[1]);
    kp[0] = __float2bfloat16(kr * c - ki * si);
    kp[1] = __float2bfloat16(kr * si + ki * c);
}

// ---------------------------------------------------------------- chunked MFMA flash attention
__global__ __launch_bounds__(256, 3) void flash_attn_chunk(const bf16* __restrict__ qkv,
                                                           float* __restrict__ Opart,
                                                           float* __restrict__ Mpart) {
    __shared__ bf16 Ks[64][136];    // key-major, pad 8 (stride 272 B)
    __shared__ bf16 Vt[128][72];    // dim-major, pad 8 (stride 144 B)
    __shared__ bf16 Ps[64][72];

    const int h = blockIdx.y;
    int rem = blockIdx.x, it = 0;
    for (;;) { int nc = (it >> 3) + 1; if (rem < nc) break; rem -= nc; ++it; }
    const int c = rem;
    const int q8 = it >> 3, r8 = it & 7;
    const int slot = h * NCHUNK_TOT + (q8 + 1) * (4 * q8 + r8) + c;
    const int j0 = c * 8;
    const int j1 = (j0 + 8 < it + 1) ? (j0 + 8) : (it + 1);

    const int t = threadIdx.x;
    const int lane = t & 63;
    const int w = t >> 6;
    const int quad = lane >> 4;
    const int l16 = lane & 15;
    const int s0 = it * 64;
    const float sl2 = (float)(0.08838834764831845 * 1.4426950408889634);

    short8 qreg[4];
    {
        const bf16* qrow = qkv + (size_t)(s0 + 16 * w + l16) * QKVN + h * HD + quad * 8;
#pragma unroll
        for (int ks = 0; ks < 4; ++ks)
            qreg[ks] = *(const short8*)(qrow + ks * 32);
    }

    floatx4 O[8] = {};
    float m_i[4], l_i[4];
#pragma unroll
    for (int r = 0; r < 4; ++r) { m_i[r] = -INFINITY; l_i[r] = 0.f; }

    const int vkg = t >> 5;
    const int vdg = t & 31;

    for (int jt = j0; jt < j1; ++jt) {
        const int tb = jt * 64;
        __syncthreads();

#pragma unroll
        for (int u = 0; u < 4; ++u) {
            int vv = t + 256 * u;
            int kr = vv >> 4, kc = vv & 15;
            *(uint4*)&Ks[kr][kc * 8] =
                *(const uint4*)(qkv + (size_t)(tb + kr) * QKVN + DIM + h * HD + kc * 8);
        }
        {
            short4v vr[8];
#pragma unroll
            for (int kk = 0; kk < 8; ++kk)
                vr[kk] = *(const short4v*)(qkv + (size_t)(tb + vkg * 8 + kk) * QKVN + 2 * DIM + h * HD + vdg * 4);
#pragma unroll
            for (int dd = 0; dd < 4; ++dd) {
                short8 wv;
#pragma unroll
                for (int kk = 0; kk < 8; ++kk) wv[kk] = vr[kk][dd];
                *(short8*)&Vt[vdg * 4 + dd][vkg * 8] = wv;
            }
        }
        __syncthreads();

        floatx4 sacc[4] = {};
#pragma unroll
        for (int ks = 0; ks < 4; ++ks) {
            short8 kb[4];
#pragma unroll
            for (int nt = 0; nt < 4; ++nt)
                kb[nt] = *(const short8*)&Ks[nt * 16 + l16][ks * 32 + quad * 8];
#pragma unroll
            for (int nt = 0; nt < 4; ++nt)
                sacc[nt] = __builtin_amdgcn_mfma_f32_16x16x32_bf16(qreg[ks], kb[nt], sacc[nt], 0, 0, 0);
        }

        float alpha[4];
#pragma unroll
        for (int r = 0; r < 4; ++r) {
            float mx = -INFINITY;
#pragma unroll
            for (int nt = 0; nt < 4; ++nt) {
                float s = sacc[nt][r] * sl2;
                if (jt == it && (nt * 16 + l16) > (16 * w + quad * 4 + r)) s = -INFINITY;
                sacc[nt][r] = s;
                mx = fmaxf(mx, s);
            }
#pragma unroll
            for (int off = 1; off < 16; off <<= 1)
                mx = fmaxf(mx, __shfl_xor(mx, off, 64));
            float mn = fmaxf(m_i[r], mx);
            alpha[r] = exp2f(m_i[r] - mn);
            float lsum = 0.f;
#pragma unroll
            for (int nt = 0; nt < 4; ++nt) {
                float e = exp2f(sacc[nt][r] - mn);
                sacc[nt][r] = e;
                lsum += e;
            }
#pragma unroll
            for (int off = 1; off < 16; off <<= 1)
                lsum += __shfl_xor(lsum, off, 64);
            l_i[r] = l_i[r] * alpha[r] + lsum;
            m_i[r] = mn;
        }

#pragma unroll
        for (int nt = 0; nt < 4; ++nt)
#pragma unroll
            for (int r = 0; r < 4; ++r)
                Ps[16 * w + quad * 4 + r][nt * 16 + l16] = __float2bfloat16(sacc[nt][r]);

#pragma unroll
        for (int nt = 0; nt < 8; ++nt)
#pragma unroll
            for (int r = 0; r < 4; ++r)
                O[nt][r] *= alpha[r];

#pragma unroll
        for (int ks = 0; ks < 2; ++ks) {
            short8 pa = *(const short8*)&Ps[16 * w + l16][ks * 32 + quad * 8];
#pragma unroll
            for (int nt = 0; nt < 8; ++nt) {
                short8 vb = *(const short8*)&Vt[nt * 16 + l16][ks * 32 + quad * 8];
                O[nt] = __builtin_amdgcn_mfma_f32_16x16x32_bf16(pa, vb, O[nt], 0, 0, 0);
            }
        }
    }

    float* Op = Opart + (size_t)slot * (64 * 128);
    float* Mp = Mpart + (size_t)slot * 128;
    if (l16 == 0) {
#pragma unroll
        for (int r = 0; r < 4; ++r) {
            int row = 16 * w + quad * 4 + r;
            Mp[row] = m_i[r];
            Mp[64 + row] = l_i[r];
        }
    }
#pragma unroll
    for (int r = 0; r < 4; ++r) {
        int row = 16 * w + quad * 4 + r;
#pragma unroll
        for (int nt = 0; nt < 8; ++nt)
            Op[row * 128 + nt * 16 + l16] = O[nt][r];
    }
}

// ---------------------------------------------------------------- combine partials -> bf16 out
__global__ __launch_bounds__(256) void attn_combine(const float* __restrict__ Opart,
                                                    const float* __restrict__ Mpart,
                                                    bf16* __restrict__ out) {
    const int it = blockIdx.x;
    const int h = blockIdx.y;
    const int nch = (it >> 3) + 1;
    const int q8 = it >> 3, r8 = it & 7;
    const int base = h * NCHUNK_TOT + (q8 + 1) * (4 * q8 + r8);
    const int t = threadIdx.x;
    const int row = t >> 2;
    const int dq = t & 3;

    float mv[4], wgt[4];
    float M = -INFINITY;
#pragma unroll
    for (int c = 0; c < 4; ++c) {
        if (c < nch) {
            mv[c] = Mpart[(size_t)(base + c) * 128 + row];
            M = fmaxf(M, mv[c]);
        }
    }
    float L = 0.f;
#pragma unroll
    for (int c = 0; c < 4; ++c) {
        if (c < nch) {
            wgt[c] = exp2f(mv[c] - M);
            L += Mpart[(size_t)(base + c) * 128 + 64 + row] * wgt[c];
        }
    }
    float inv = 1.f / L;

    float acc[32] = {};
#pragma unroll
    for (int c = 0; c < 4; ++c) {
        if (c < nch) {
            const float* Oc = Opart + ((size_t)(base + c) * 64 + row) * 128 + dq * 32;
            float wc = wgt[c];
#pragma unroll
            for (int k = 0; k < 8; ++k) {
                float4 v = *(const float4*)&Oc[k * 4];
                acc[k * 4 + 0] += wc * v.x;
                acc[k * 4 + 1] += wc * v.y;
                acc[k * 4 + 2] += wc * v.z;
                acc[k * 4 + 3] += wc * v.w;
            }
        }
    }

    bf16* orow = out + (size_t)(it * 64 + row) * DIM + h * HD + dq * 32;
#pragma unroll
    for (int k2 = 0; k2 < 4; ++k2) {
        short8 pk;
#pragma unroll
        for (int e = 0; e < 8; ++e)
            pk[e] = bfbits(acc[k2 * 8 + e] * inv);
        *(short8*)&orow[k2 * 8] = pk;
    }
}

// ---------------------------------------------------------------- launch
extern "C" void kernel_launch(void* const* d_in, const int* in_sizes, int n_in,
                              void* d_out, int out_size, void* d_ws, size_t ws_size,
                              hipStream_t stream) {
    const float* x      = (const float*)d_in[0];
    const float* f_cos  = (const float*)d_in[1];
    const float* f_sin  = (const float*)d_in[2];
    // d_in[3] = mask : ignored (causality analytic)
    const float* wq     = (const float*)d_in[4];
    const float* wk     = (const float*)d_in[5];
    const float* wv     = (const float*)d_in[6];
    const float* wo     = (const float*)d_in[7];
    const float* w1     = (const float*)d_in[8];
    const float* w2     = (const float*)d_in[9];
    const float* w3     = (const float*)d_in[10];
    const float* g_attn = (const float*)d_in[11];
    const float* g_ffn  = (const float*)d_in[12];
    float* out = (float*)d_out;

    char* base = (char*)d_ws;
    size_t off = 0;
    auto alloc = [&](size_t bytes) { void* p = base + off; off += (bytes + 255) & ~255ULL; return p; };
    bf16* qkvt = (bf16*)alloc((size_t)QKVN * DIM * 2);
    bf16* wot  = (bf16*)alloc((size_t)DIM * DIM * 2);
    bf16* w1t  = (bf16*)alloc((size_t)HIDDEN * DIM * 2);
    bf16* w3t  = (bf16*)alloc((size_t)HIDDEN * DIM * 2);
    bf16* w2t  = (bf16*)alloc((size_t)DIM * HIDDEN * 2);
    bf16* xbuf = (bf16*)alloc((size_t)SEQ * DIM * 2);
    bf16* qkv  = (bf16*)alloc((size_t)SEQ * QKVN * 2);
    float* h   = (float*)alloc((size_t)SEQ * DIM * 4);
    bf16* t1   = (bf16*)alloc((size_t)SEQ * HIDDEN * 2);
    float* Opart = (float*)alloc((size_t)NHEAD * NCHUNK_TOT * 64 * 128 * 4);
    float* Mpart = (float*)alloc((size_t)NHEAD * NCHUNK_TOT * 128 * 4);
    // split-K partials alias weight buffers that are dead by the W2 GEMM:
    // qkvt (24 MB, dead after QKV GEMM), w1t (23 MB, dead after gemm_w13).
    float* p0 = (float*)qkvt;   // 16.7 MB needed
    float* p1 = (float*)w1t;

    dim3 blk(256);

    cvt_t_kernel<<<dim3(DIM / 64, DIM / 64), blk, 0, stream>>>(wq, qkvt, DIM, DIM);
    cvt_t_kernel<<<dim3(DIM / 64, DIM / 64), blk, 0, stream>>>(wk, qkvt + (size_t)DIM * DIM, DIM, DIM);
    cvt_t_kernel<<<dim3(DIM / 64, DIM / 64), blk, 0, stream>>>(wv, qkvt + (size_t)2 * DIM * DIM, DIM, DIM);
    cvt_t_kernel<<<dim3(DIM / 64, DIM / 64), blk, 0, stream>>>(wo, wot, DIM, DIM);
    cvt_t_kernel<<<dim3(HIDDEN / 64, DIM / 64), blk, 0, stream>>>(w1, w1t, DIM, HIDDEN);
    cvt_t_kernel<<<dim3(HIDDEN / 64, DIM / 64), blk, 0, stream>>>(w3, w3t, DIM, HIDDEN);
    cvt_t_kernel<<<dim3(DIM / 64, HIDDEN / 64), blk, 0, stream>>>(w2, w2t, HIDDEN, DIM);

    rmsnorm_kernel<<<SEQ, blk, 0, stream>>>(x, g_attn, xbuf);
    gemm_wide<0><<<dim3(QKVN / 256, SEQ / 128), blk, 0, stream>>>(xbuf, qkvt, qkv, DIM, 0, DIM, QKVN);
    rope_kernel<<<(SEQ * NHEAD * HD / 2) / 256, blk, 0, stream>>>(qkv, f_cos, f_sin);
    flash_attn_chunk<<<dim3(NCHUNK_TOT, NHEAD), blk, 0, stream>>>(qkv, Opart, Mpart);
    attn_combine<<<dim3(SEQ / 64, NHEAD), blk, 0, stream>>>(Opart, Mpart, xbuf);
    gemm_bf16<1><<<dim3(DIM / 128, SEQ / 128), blk, 0, stream>>>(xbuf, wot, h, x, DIM, DIM);
    rmsnorm_kernel<<<SEQ, blk, 0, stream>>>(h, g_ffn, xbuf);
    gemm_w13<<<dim3(HIDDEN / 128, SEQ / 128), blk, 0, stream>>>(xbuf, w1t, w3t, t1, DIM, HIDDEN);
    // W2 split-K: two wide dispatches (K halves) writing raw f32 partials,
    // then combine adds residual h.
    gemm_wide<4><<<dim3(DIM / 256, SEQ / 128), blk, 0, stream>>>(t1, w2t, p0, HIDDEN, 0,    HIDDEN / 2, DIM);
    gemm_wide<4><<<dim3(DIM / 256, SEQ / 128), blk, 0, stream>>>(t1, w2t, p1, HIDDEN, HIDDEN / 2, HIDDEN / 2, DIM);
    combine2<<<dim3(SEQ * DIM / 1024), blk, 0, stream>>>(p0, p1, h, out);
}

// Round 6
// 764.652 us; speedup vs baseline: 1.0744x; 1.0744x over previous
//
#include <hip/hip_runtime.h>
#include <hip/hip_bf16.h>
#include <math.h>

#define SEQ 2048
#define DIM 2048
#define NHEAD 16
#define HD 128
#define HIDDEN 5632
#define QKVN 6144
#define NCHUNK_TOT 80   // sum_{it=0}^{31} (it/8 + 1)
constexpr float EPS = 1e-6f;

typedef __hip_bfloat16 bf16;
using short8  = __attribute__((ext_vector_type(8))) short;
using short4v = __attribute__((ext_vector_type(4))) short;
using floatx4 = __attribute__((ext_vector_type(4))) float;

__device__ inline void gl_lds16(const void* g, void* l) {
    __builtin_amdgcn_global_load_lds((const __attribute__((address_space(1))) void*)g,
                                     (__attribute__((address_space(3))) void*)l, 16, 0, 0);
}

__device__ inline short bfbits(float f) {
    bf16 b = __float2bfloat16(f);
    return *(const short*)&b;
}

// ---------------------------------------------------------------- rmsnorm (f32 in, bf16 out)
__global__ __launch_bounds__(256) void rmsnorm_kernel(const float* __restrict__ x,
                                                      const float* __restrict__ g,
                                                      bf16* __restrict__ out) {
    int row = blockIdx.x;
    const float4* xr = (const float4*)(x + (size_t)row * DIM);
    const float4* g4 = (const float4*)g;
    float4 v[2];
    float ss = 0.f;
#pragma unroll
    for (int i = 0; i < 2; ++i) {
        v[i] = xr[threadIdx.x + 256 * i];
        ss += v[i].x * v[i].x + v[i].y * v[i].y + v[i].z * v[i].z + v[i].w * v[i].w;
    }
    __shared__ float red[256];
    red[threadIdx.x] = ss;
    __syncthreads();
    for (int s = 128; s > 0; s >>= 1) {
        if (threadIdx.x < s) red[threadIdx.x] += red[threadIdx.x + s];
        __syncthreads();
    }
    float scale = rsqrtf(red[0] / (float)DIM + EPS);
    bf16* orow = out + (size_t)row * DIM;
#pragma unroll
    for (int i = 0; i < 2; ++i) {
        float4 gv = g4[threadIdx.x + 256 * i];
        short4v o;
        o[0] = bfbits(v[i].x * scale * gv.x);
        o[1] = bfbits(v[i].y * scale * gv.y);
        o[2] = bfbits(v[i].z * scale * gv.z);
        o[3] = bfbits(v[i].w * scale * gv.w);
        *(short4v*)&orow[(threadIdx.x + 256 * i) * 4] = o;
    }
}

// ---------------------------------------------------------------- weight cast+transpose
__global__ __launch_bounds__(256) void cvt_t_kernel(const float* __restrict__ in,
                                                    bf16* __restrict__ out,
                                                    int K, int N) {
    __shared__ bf16 L[64][72];
    const int nb = blockIdx.x * 64, kb = blockIdx.y * 64;
    const int t = threadIdx.x;
    const int nq = t & 15;   // n group of 4
    const int kq = t >> 4;   // k group of 4
    float4 v[4];
#pragma unroll
    for (int i = 0; i < 4; ++i)
        v[i] = *(const float4*)&in[(size_t)(kb + kq * 4 + i) * N + nb + nq * 4];
#pragma unroll
    for (int j = 0; j < 4; ++j) {
        short4v o;
#pragma unroll
        for (int i = 0; i < 4; ++i)
            o[i] = bfbits(((const float*)&v[i])[j]);
        *(short4v*)&L[nq * 4 + j][kq * 4] = o;
    }
    __syncthreads();
    const int c8 = t & 7, rw = t >> 3;
#pragma unroll
    for (int p = 0; p < 2; ++p) {
        int row = rw + p * 32;
        *(short8*)&out[(size_t)(nb + row) * K + kb + c8 * 8] = *(const short8*)&L[row][c8 * 8];
    }
}

// ---------------------------------------------------------------- bf16 MFMA GEMM (128x128, 2-phase)
template <int MODE>
__global__ __launch_bounds__(256) void gemm_bf16(const bf16* __restrict__ A,
                                                 const bf16* __restrict__ Bt,
                                                 void* __restrict__ Cv,
                                                 const float* __restrict__ R,
                                                 int K, int ldc) {
    __shared__ bf16 Asm[2][128 * 32];
    __shared__ bf16 Bsm[2][128 * 32];
    const int t = threadIdx.x;

    int wg = blockIdx.y * gridDim.x + blockIdx.x;
    {
        const int nwg = gridDim.x * gridDim.y;
        const int q = nwg >> 3, r = nwg & 7;
        const int xcd = wg & 7, loc = wg >> 3;
        wg = (xcd < r ? xcd * (q + 1) : r * (q + 1) + (xcd - r) * q) + loc;
    }
    const int m0 = (wg / gridDim.x) * 128;
    const int n0 = (wg % gridDim.x) * 128;

    const int lane = t & 63;
    const int wave = t >> 6;
    const int wr = wave >> 1, wc = wave & 1;
    const int quad = lane >> 4;
    const int l16 = lane & 15;

    floatx4 acc[4][4] = {};

    const int ar = t >> 2;
    const int ak = (t & 3) * 8;
    const bf16* Ag = A + (size_t)(m0 + ar) * K + ak;
    const bf16* Bg = Bt + (size_t)(n0 + ar) * K + ak;
    const size_t half = (size_t)64 * K;

    gl_lds16(Ag, Asm[0] + t * 8);
    gl_lds16(Ag + half, Asm[0] + t * 8 + 64 * 32);
    gl_lds16(Bg, Bsm[0] + t * 8);
    gl_lds16(Bg + half, Bsm[0] + t * 8 + 64 * 32);
    __syncthreads();

    int cur = 0;
    for (int k0 = 0; k0 < K; k0 += 32) {
        if (k0 + 32 < K) {
            const int nb = cur ^ 1;
            gl_lds16(Ag + k0 + 32, Asm[nb] + t * 8);
            gl_lds16(Ag + k0 + 32 + half, Asm[nb] + t * 8 + 64 * 32);
            gl_lds16(Bg + k0 + 32, Bsm[nb] + t * 8);
            gl_lds16(Bg + k0 + 32 + half, Bsm[nb] + t * 8 + 64 * 32);
        }

        const bf16* As = Asm[cur];
        const bf16* Bs = Bsm[cur];
        short8 af[4], bfr[4];
#pragma unroll
        for (int i = 0; i < 4; ++i)
            af[i] = *(const short8*)(As + (wr * 64 + i * 16 + l16) * 32 + quad * 8);
#pragma unroll
        for (int j = 0; j < 4; ++j)
            bfr[j] = *(const short8*)(Bs + (wc * 64 + j * 16 + l16) * 32 + quad * 8);
#pragma unroll
        for (int i = 0; i < 4; ++i)
#pragma unroll
            for (int j = 0; j < 4; ++j)
                acc[i][j] = __builtin_amdgcn_mfma_f32_16x16x32_bf16(af[i], bfr[j], acc[i][j], 0, 0, 0);

        __syncthreads();
        cur ^= 1;
    }

#pragma unroll
    for (int i = 0; i < 4; ++i) {
#pragma unroll
        for (int j = 0; j < 4; ++j) {
#pragma unroll
            for (int r = 0; r < 4; ++r) {
                int m = m0 + wr * 64 + i * 16 + quad * 4 + r;
                int n = n0 + wc * 64 + j * 16 + l16;
                size_t idx = (size_t)m * ldc + n;
                float v = acc[i][j][r];
                if (MODE == 0) {
                    ((bf16*)Cv)[idx] = __float2bfloat16(v);
                } else {
                    ((float*)Cv)[idx] = v + R[idx];
                }
            }
        }
    }
}

// ---------------------------------------------------------------- QKV 3-panel wide GEMM (128x384)
// N = 6144 = 16 blocks of 384 -> grid 16x16 = 256 blocks = EXACTLY 1/CU
// (round-5 lesson: wide tiles only with uniform machine fill). A staged once
// per K-step for 48 MFMA/wave: 96 FLOP/B staged vs 64 (128x128).
__global__ __launch_bounds__(256) void gemm_qkv3(const bf16* __restrict__ A,
                                                 const bf16* __restrict__ Bt,
                                                 bf16* __restrict__ C,
                                                 int K, int ldc) {
    __shared__ bf16 Asm[2][128 * 32];
    __shared__ bf16 Bsm[3][2][128 * 32];
    const int t = threadIdx.x;

    int wg = blockIdx.y * gridDim.x + blockIdx.x;
    {
        const int nwg = gridDim.x * gridDim.y;   // 256, div by 8 -> bijective
        const int q = nwg >> 3, r = nwg & 7;
        const int xcd = wg & 7, loc = wg >> 3;
        wg = (xcd < r ? xcd * (q + 1) : r * (q + 1) + (xcd - r) * q) + loc;
    }
    const int m0 = (wg / gridDim.x) * 128;
    const int n0 = (wg % gridDim.x) * 384;

    const int lane = t & 63;
    const int wave = t >> 6;
    const int wr = wave >> 1, wc = wave & 1;
    const int quad = lane >> 4;
    const int l16 = lane & 15;

    floatx4 acc[3][4][4] = {};

    const int ar = t >> 2;
    const int ak = (t & 3) * 8;
    const bf16* Ag = A + (size_t)(m0 + ar) * K + ak;
    const bf16* Bg[3];
#pragma unroll
    for (int p = 0; p < 3; ++p)
        Bg[p] = Bt + (size_t)(n0 + p * 128 + ar) * K + ak;
    const size_t half = (size_t)64 * K;

    auto stage = [&](int k, int buf) {
        gl_lds16(Ag + k, Asm[buf] + t * 8);
        gl_lds16(Ag + k + half, Asm[buf] + t * 8 + 64 * 32);
#pragma unroll
        for (int p = 0; p < 3; ++p) {
            gl_lds16(Bg[p] + k, Bsm[p][buf] + t * 8);
            gl_lds16(Bg[p] + k + half, Bsm[p][buf] + t * 8 + 64 * 32);
        }
    };

    stage(0, 0);
    __syncthreads();

    int cur = 0;
    for (int k0 = 0; k0 < K; k0 += 32) {
        if (k0 + 32 < K) stage(k0 + 32, cur ^ 1);

        const bf16* As = Asm[cur];
        short8 af[4], bfr[4];
#pragma unroll
        for (int i = 0; i < 4; ++i)
            af[i] = *(const short8*)(As + (wr * 64 + i * 16 + l16) * 32 + quad * 8);

#pragma unroll
        for (int p = 0; p < 3; ++p) {
            const bf16* Bs = Bsm[p][cur];
#pragma unroll
            for (int j = 0; j < 4; ++j)
                bfr[j] = *(const short8*)(Bs + (wc * 64 + j * 16 + l16) * 32 + quad * 8);
#pragma unroll
            for (int i = 0; i < 4; ++i)
#pragma unroll
                for (int j = 0; j < 4; ++j)
                    acc[p][i][j] = __builtin_amdgcn_mfma_f32_16x16x32_bf16(af[i], bfr[j], acc[p][i][j], 0, 0, 0);
        }

        __syncthreads();
        cur ^= 1;
    }

#pragma unroll
    for (int p = 0; p < 3; ++p)
#pragma unroll
        for (int i = 0; i < 4; ++i)
#pragma unroll
            for (int j = 0; j < 4; ++j)
#pragma unroll
                for (int r = 0; r < 4; ++r) {
                    int m = m0 + wr * 64 + i * 16 + quad * 4 + r;
                    int n = n0 + p * 128 + wc * 64 + j * 16 + l16;
                    C[(size_t)m * ldc + n] = __float2bfloat16(acc[p][i][j][r]);
                }
}

// ---------------------------------------------------------------- W2 wide split-K GEMM (128x256, K/2 per z)
// grid (8,16,2) = 256 blocks = 1/CU uniform. blockIdx.z picks K-half and
// partial buffer. f32 partials; combine2 adds p0+p1+residual.
__global__ __launch_bounds__(256, 2) void gemm_w2sk(const bf16* __restrict__ A,
                                                    const bf16* __restrict__ Bt,
                                                    float* __restrict__ p0,
                                                    float* __restrict__ p1,
                                                    int ldk, int klen, int ldc) {
    __shared__ bf16 Asm[2][128 * 32];
    __shared__ bf16 B1s[2][128 * 32];
    __shared__ bf16 B3s[2][128 * 32];
    const int t = threadIdx.x;
    const int kbase = blockIdx.z * klen;
    float* outp = blockIdx.z ? p1 : p0;

    int wg = blockIdx.y * gridDim.x + blockIdx.x;
    {
        const int nwg = gridDim.x * gridDim.y;   // 128, div by 8 -> bijective
        const int q = nwg >> 3, r = nwg & 7;
        const int xcd = wg & 7, loc = wg >> 3;
        wg = (xcd < r ? xcd * (q + 1) : r * (q + 1) + (xcd - r) * q) + loc;
    }
    const int m0 = (wg / gridDim.x) * 128;
    const int n0 = (wg % gridDim.x) * 256;

    const int lane = t & 63;
    const int wave = t >> 6;
    const int wr = wave >> 1, wc = wave & 1;
    const int quad = lane >> 4;
    const int l16 = lane & 15;

    floatx4 acc1[4][4] = {};
    floatx4 acc3[4][4] = {};

    const int ar = t >> 2;
    const int ak = (t & 3) * 8;
    const bf16* Ag  = A  + (size_t)(m0 + ar) * ldk + kbase + ak;
    const bf16* B1g = Bt + (size_t)(n0 + ar) * ldk + kbase + ak;
    const bf16* B3g = Bt + (size_t)(n0 + 128 + ar) * ldk + kbase + ak;
    const size_t half = (size_t)64 * ldk;

    auto stage = [&](int k, int buf) {
        gl_lds16(Ag + k, Asm[buf] + t * 8);
        gl_lds16(Ag + k + half, Asm[buf] + t * 8 + 64 * 32);
        gl_lds16(B1g + k, B1s[buf] + t * 8);
        gl_lds16(B1g + k + half, B1s[buf] + t * 8 + 64 * 32);
        gl_lds16(B3g + k, B3s[buf] + t * 8);
        gl_lds16(B3g + k + half, B3s[buf] + t * 8 + 64 * 32);
    };

    stage(0, 0);
    __syncthreads();

    int cur = 0;
    for (int k0 = 0; k0 < klen; k0 += 32) {
        if (k0 + 32 < klen) stage(k0 + 32, cur ^ 1);

        const bf16* As = Asm[cur];
        short8 af[4], bfr[4];
#pragma unroll
        for (int i = 0; i < 4; ++i)
            af[i] = *(const short8*)(As + (wr * 64 + i * 16 + l16) * 32 + quad * 8);

        const bf16* B1 = B1s[cur];
#pragma unroll
        for (int j = 0; j < 4; ++j)
            bfr[j] = *(const short8*)(B1 + (wc * 64 + j * 16 + l16) * 32 + quad * 8);
#pragma unroll
        for (int i = 0; i < 4; ++i)
#pragma unroll
            for (int j = 0; j < 4; ++j)
                acc1[i][j] = __builtin_amdgcn_mfma_f32_16x16x32_bf16(af[i], bfr[j], acc1[i][j], 0, 0, 0);

        const bf16* B3 = B3s[cur];
#pragma unroll
        for (int j = 0; j < 4; ++j)
            bfr[j] = *(const short8*)(B3 + (wc * 64 + j * 16 + l16) * 32 + quad * 8);
#pragma unroll
        for (int i = 0; i < 4; ++i)
#pragma unroll
            for (int j = 0; j < 4; ++j)
                acc3[i][j] = __builtin_amdgcn_mfma_f32_16x16x32_bf16(af[i], bfr[j], acc3[i][j], 0, 0, 0);

        __syncthreads();
        cur ^= 1;
    }

#pragma unroll
    for (int i = 0; i < 4; ++i)
#pragma unroll
        for (int j = 0; j < 4; ++j)
#pragma unroll
            for (int r = 0; r < 4; ++r) {
                int m = m0 + wr * 64 + i * 16 + quad * 4 + r;
                int n = n0 + wc * 64 + j * 16 + l16;
                outp[(size_t)m * ldc + n]       = acc1[i][j][r];
                outp[(size_t)m * ldc + n + 128] = acc3[i][j][r];
            }
}

// ---------------------------------------------------------------- fused W1/W3 SwiGLU GEMM
__global__ __launch_bounds__(256, 2) void gemm_w13(const bf16* __restrict__ A,
                                                   const bf16* __restrict__ B1t,
                                                   const bf16* __restrict__ B3t,
                                                   bf16* __restrict__ C,
                                                   int K, int ldc) {
    __shared__ bf16 Asm[2][128 * 32];
    __shared__ bf16 B1s[2][128 * 32];
    __shared__ bf16 B3s[2][128 * 32];
    const int t = threadIdx.x;

    int wg = blockIdx.y * gridDim.x + blockIdx.x;
    {
        const int nwg = gridDim.x * gridDim.y;
        const int q = nwg >> 3, r = nwg & 7;
        const int xcd = wg & 7, loc = wg >> 3;
        wg = (xcd < r ? xcd * (q + 1) : r * (q + 1) + (xcd - r) * q) + loc;
    }
    const int m0 = (wg / gridDim.x) * 128;
    const int n0 = (wg % gridDim.x) * 128;

    const int lane = t & 63;
    const int wave = t >> 6;
    const int wr = wave >> 1, wc = wave & 1;
    const int quad = lane >> 4;
    const int l16 = lane & 15;

    floatx4 acc1[4][4] = {};
    floatx4 acc3[4][4] = {};

    const int ar = t >> 2;
    const int ak = (t & 3) * 8;
    const bf16* Ag  = A   + (size_t)(m0 + ar) * K + ak;
    const bf16* B1g = B1t + (size_t)(n0 + ar) * K + ak;
    const bf16* B3g = B3t + (size_t)(n0 + ar) * K + ak;
    const size_t half = (size_t)64 * K;

    auto stage = [&](int k, int buf) {
        gl_lds16(Ag + k, Asm[buf] + t * 8);
        gl_lds16(Ag + k + half, Asm[buf] + t * 8 + 64 * 32);
        gl_lds16(B1g + k, B1s[buf] + t * 8);
        gl_lds16(B1g + k + half, B1s[buf] + t * 8 + 64 * 32);
        gl_lds16(B3g + k, B3s[buf] + t * 8);
        gl_lds16(B3g + k + half, B3s[buf] + t * 8 + 64 * 32);
    };

    stage(0, 0);
    __syncthreads();

    int cur = 0;
    for (int k0 = 0; k0 < K; k0 += 32) {
        if (k0 + 32 < K) stage(k0 + 32, cur ^ 1);

        const bf16* As = Asm[cur];
        short8 af[4], bfr[4];
#pragma unroll
        for (int i = 0; i < 4; ++i)
            af[i] = *(const short8*)(As + (wr * 64 + i * 16 + l16) * 32 + quad * 8);

        const bf16* B1 = B1s[cur];
#pragma unroll
        for (int j = 0; j < 4; ++j)
            bfr[j] = *(const short8*)(B1 + (wc * 64 + j * 16 + l16) * 32 + quad * 8);
#pragma unroll
        for (int i = 0; i < 4; ++i)
#pragma unroll
            for (int j = 0; j < 4; ++j)
                acc1[i][j] = __builtin_amdgcn_mfma_f32_16x16x32_bf16(af[i], bfr[j], acc1[i][j], 0, 0, 0);

        const bf16* B3 = B3s[cur];
#pragma unroll
        for (int j = 0; j < 4; ++j)
            bfr[j] = *(const short8*)(B3 + (wc * 64 + j * 16 + l16) * 32 + quad * 8);
#pragma unroll
        for (int i = 0; i < 4; ++i)
#pragma unroll
            for (int j = 0; j < 4; ++j)
                acc3[i][j] = __builtin_amdgcn_mfma_f32_16x16x32_bf16(af[i], bfr[j], acc3[i][j], 0, 0, 0);

        __syncthreads();
        cur ^= 1;
    }

#pragma unroll
    for (int i = 0; i < 4; ++i) {
#pragma unroll
        for (int j = 0; j < 4; ++j) {
#pragma unroll
            for (int r = 0; r < 4; ++r) {
                int m = m0 + wr * 64 + i * 16 + quad * 4 + r;
                int n = n0 + wc * 64 + j * 16 + l16;
                float v1 = acc1[i][j][r];
                float v3 = acc3[i][j][r];
                float s = v1 / (1.f + __expf(-v1));
                C[(size_t)m * ldc + n] = __float2bfloat16(s * v3);
            }
        }
    }
}

// ---------------------------------------------------------------- split-K combine: out = p0+p1+h
__global__ __launch_bounds__(256) void combine2(const float* __restrict__ p0,
                                                const float* __restrict__ p1,
                                                const float* __restrict__ h,
                                                float* __restrict__ out) {
    size_t i = ((size_t)blockIdx.x * 256 + threadIdx.x) * 4;
    float4 a = *(const float4*)&p0[i];
    float4 b = *(const float4*)&p1[i];
    float4 c = *(const float4*)&h[i];
    float4 o;
    o.x = a.x + b.x + c.x;
    o.y = a.y + b.y + c.y;
    o.z = a.z + b.z + c.z;
    o.w = a.w + b.w + c.w;
    *(float4*)&out[i] = o;
}

// ---------------------------------------------------------------- RoPE (in-place, bf16 qkv buffer)
__global__ __launch_bounds__(256) void rope_kernel(bf16* __restrict__ qkv,
                                                   const float* __restrict__ cs,
                                                   const float* __restrict__ sn) {
    int idx = blockIdx.x * 256 + threadIdx.x;
    int d2 = idx % (HD / 2);
    int rest = idx / (HD / 2);
    int h = rest % NHEAD;
    int s = rest / NHEAD;
    float c = cs[s * (HD / 2) + d2];
    float si = sn[s * (HD / 2) + d2];
    bf16* qp = qkv + (size_t)s * QKVN + h * HD + 2 * d2;
    bf16* kp = qp + DIM;
    float qr = __bfloat162float(qp[0]), qi = __bfloat162float(qp[1]);
    qp[0] = __float2bfloat16(qr * c - qi * si);
    qp[1] = __float2bfloat16(qr * si + qi * c);
    float kr = __bfloat162float(kp[0]), ki = __bfloat162float(kp[1]);
    kp[0] = __float2bfloat16(kr * c - ki * si);
    kp[1] = __float2bfloat16(kr * si + ki * c);
}

// ---------------------------------------------------------------- chunked MFMA flash attention
__global__ __launch_bounds__(256, 3) void flash_attn_chunk(const bf16* __restrict__ qkv,
                                                           float* __restrict__ Opart,
                                                           float* __restrict__ Mpart) {
    __shared__ bf16 Ks[64][136];    // key-major, pad 8 (stride 272 B)
    __shared__ bf16 Vt[128][72];    // dim-major, pad 8 (stride 144 B)
    __shared__ bf16 Ps[64][72];

    const int h = blockIdx.y;
    int rem = blockIdx.x, it = 0;
    for (;;) { int nc = (it >> 3) + 1; if (rem < nc) break; rem -= nc; ++it; }
    const int c = rem;
    const int q8 = it >> 3, r8 = it & 7;
    const int slot = h * NCHUNK_TOT + (q8 + 1) * (4 * q8 + r8) + c;
    const int j0 = c * 8;
    const int j1 = (j0 + 8 < it + 1) ? (j0 + 8) : (it + 1);

    const int t = threadIdx.x;
    const int lane = t & 63;
    const int w = t >> 6;
    const int quad = lane >> 4;
    const int l16 = lane & 15;
    const int s0 = it * 64;
    const float sl2 = (float)(0.08838834764831845 * 1.4426950408889634);

    short8 qreg[4];
    {
        const bf16* qrow = qkv + (size_t)(s0 + 16 * w + l16) * QKVN + h * HD + quad * 8;
#pragma unroll
        for (int ks = 0; ks < 4; ++ks)
            qreg[ks] = *(const short8*)(qrow + ks * 32);
    }

    floatx4 O[8] = {};
    float m_i[4], l_i[4];
#pragma unroll
    for (int r = 0; r < 4; ++r) { m_i[r] = -INFINITY; l_i[r] = 0.f; }

    const int vkg = t >> 5;
    const int vdg = t & 31;

    for (int jt = j0; jt < j1; ++jt) {
        const int tb = jt * 64;
        __syncthreads();

#pragma unroll
        for (int u = 0; u < 4; ++u) {
            int vv = t + 256 * u;
            int kr = vv >> 4, kc = vv & 15;
            *(uint4*)&Ks[kr][kc * 8] =
                *(const uint4*)(qkv + (size_t)(tb + kr) * QKVN + DIM + h * HD + kc * 8);
        }
        {
            short4v vr[8];
#pragma unroll
            for (int kk = 0; kk < 8; ++kk)
                vr[kk] = *(const short4v*)(qkv + (size_t)(tb + vkg * 8 + kk) * QKVN + 2 * DIM + h * HD + vdg * 4);
#pragma unroll
            for (int dd = 0; dd < 4; ++dd) {
                short8 wv;
#pragma unroll
                for (int kk = 0; kk < 8; ++kk) wv[kk] = vr[kk][dd];
                *(short8*)&Vt[vdg * 4 + dd][vkg * 8] = wv;
            }
        }
        __syncthreads();

        floatx4 sacc[4] = {};
#pragma unroll
        for (int ks = 0; ks < 4; ++ks) {
            short8 kb[4];
#pragma unroll
            for (int nt = 0; nt < 4; ++nt)
                kb[nt] = *(const short8*)&Ks[nt * 16 + l16][ks * 32 + quad * 8];
#pragma unroll
            for (int nt = 0; nt < 4; ++nt)
                sacc[nt] = __builtin_amdgcn_mfma_f32_16x16x32_bf16(qreg[ks], kb[nt], sacc[nt], 0, 0, 0);
        }

        float alpha[4];
#pragma unroll
        for (int r = 0; r < 4; ++r) {
            float mx = -INFINITY;
#pragma unroll
            for (int nt = 0; nt < 4; ++nt) {
                float s = sacc[nt][r] * sl2;
                if (jt == it && (nt * 16 + l16) > (16 * w + quad * 4 + r)) s = -INFINITY;
                sacc[nt][r] = s;
                mx = fmaxf(mx, s);
            }
#pragma unroll
            for (int off = 1; off < 16; off <<= 1)
                mx = fmaxf(mx, __shfl_xor(mx, off, 64));
            float mn = fmaxf(m_i[r], mx);
            alpha[r] = exp2f(m_i[r] - mn);
            float lsum = 0.f;
#pragma unroll
            for (int nt = 0; nt < 4; ++nt) {
                float e = exp2f(sacc[nt][r] - mn);
                sacc[nt][r] = e;
                lsum += e;
            }
#pragma unroll
            for (int off = 1; off < 16; off <<= 1)
                lsum += __shfl_xor(lsum, off, 64);
            l_i[r] = l_i[r] * alpha[r] + lsum;
            m_i[r] = mn;
        }

#pragma unroll
        for (int nt = 0; nt < 4; ++nt)
#pragma unroll
            for (int r = 0; r < 4; ++r)
                Ps[16 * w + quad * 4 + r][nt * 16 + l16] = __float2bfloat16(sacc[nt][r]);

#pragma unroll
        for (int nt = 0; nt < 8; ++nt)
#pragma unroll
            for (int r = 0; r < 4; ++r)
                O[nt][r] *= alpha[r];

#pragma unroll
        for (int ks = 0; ks < 2; ++ks) {
            short8 pa = *(const short8*)&Ps[16 * w + l16][ks * 32 + quad * 8];
#pragma unroll
            for (int nt = 0; nt < 8; ++nt) {
                short8 vb = *(const short8*)&Vt[nt * 16 + l16][ks * 32 + quad * 8];
                O[nt] = __builtin_amdgcn_mfma_f32_16x16x32_bf16(pa, vb, O[nt], 0, 0, 0);
            }
        }
    }

    float* Op = Opart + (size_t)slot * (64 * 128);
    float* Mp = Mpart + (size_t)slot * 128;
    if (l16 == 0) {
#pragma unroll
        for (int r = 0; r < 4; ++r) {
            int row = 16 * w + quad * 4 + r;
            Mp[row] = m_i[r];
            Mp[64 + row] = l_i[r];
        }
    }
#pragma unroll
    for (int r = 0; r < 4; ++r) {
        int row = 16 * w + quad * 4 + r;
#pragma unroll
        for (int nt = 0; nt < 8; ++nt)
            Op[row * 128 + nt * 16 + l16] = O[nt][r];
    }
}

// ---------------------------------------------------------------- combine partials -> bf16 out
__global__ __launch_bounds__(256) void attn_combine(const float* __restrict__ Opart,
                                                    const float* __restrict__ Mpart,
                                                    bf16* __restrict__ out) {
    const int it = blockIdx.x;
    const int h = blockIdx.y;
    const int nch = (it >> 3) + 1;
    const int q8 = it >> 3, r8 = it & 7;
    const int base = h * NCHUNK_TOT + (q8 + 1) * (4 * q8 + r8);
    const int t = threadIdx.x;
    const int row = t >> 2;
    const int dq = t & 3;

    float mv[4], wgt[4];
    float M = -INFINITY;
#pragma unroll
    for (int c = 0; c < 4; ++c) {
        if (c < nch) {
            mv[c] = Mpart[(size_t)(base + c) * 128 + row];
            M = fmaxf(M, mv[c]);
        }
    }
    float L = 0.f;
#pragma unroll
    for (int c = 0; c < 4; ++c) {
        if (c < nch) {
            wgt[c] = exp2f(mv[c] - M);
            L += Mpart[(size_t)(base + c) * 128 + 64 + row] * wgt[c];
        }
    }
    float inv = 1.f / L;

    float acc[32] = {};
#pragma unroll
    for (int c = 0; c < 4; ++c) {
        if (c < nch) {
            const float* Oc = Opart + ((size_t)(base + c) * 64 + row) * 128 + dq * 32;
            float wc = wgt[c];
#pragma unroll
            for (int k = 0; k < 8; ++k) {
                float4 v = *(const float4*)&Oc[k * 4];
                acc[k * 4 + 0] += wc * v.x;
                acc[k * 4 + 1] += wc * v.y;
                acc[k * 4 + 2] += wc * v.z;
                acc[k * 4 + 3] += wc * v.w;
            }
        }
    }

    bf16* orow = out + (size_t)(it * 64 + row) * DIM + h * HD + dq * 32;
#pragma unroll
    for (int k2 = 0; k2 < 4; ++k2) {
        short8 pk;
#pragma unroll
        for (int e = 0; e < 8; ++e)
            pk[e] = bfbits(acc[k2 * 8 + e] * inv);
        *(short8*)&orow[k2 * 8] = pk;
    }
}

// ---------------------------------------------------------------- launch
extern "C" void kernel_launch(void* const* d_in, const int* in_sizes, int n_in,
                              void* d_out, int out_size, void* d_ws, size_t ws_size,
                              hipStream_t stream) {
    const float* x      = (const float*)d_in[0];
    const float* f_cos  = (const float*)d_in[1];
    const float* f_sin  = (const float*)d_in[2];
    // d_in[3] = mask : ignored (causality analytic)
    const float* wq     = (const float*)d_in[4];
    const float* wk     = (const float*)d_in[5];
    const float* wv     = (const float*)d_in[6];
    const float* wo     = (const float*)d_in[7];
    const float* w1     = (const float*)d_in[8];
    const float* w2     = (const float*)d_in[9];
    const float* w3     = (const float*)d_in[10];
    const float* g_attn = (const float*)d_in[11];
    const float* g_ffn  = (const float*)d_in[12];
    float* out = (float*)d_out;

    char* base = (char*)d_ws;
    size_t off = 0;
    auto alloc = [&](size_t bytes) { void* p = base + off; off += (bytes + 255) & ~255ULL; return p; };
    bf16* qkvt = (bf16*)alloc((size_t)QKVN * DIM * 2);
    bf16* wot  = (bf16*)alloc((size_t)DIM * DIM * 2);
    bf16* w1t  = (bf16*)alloc((size_t)HIDDEN * DIM * 2);
    bf16* w3t  = (bf16*)alloc((size_t)HIDDEN * DIM * 2);
    bf16* w2t  = (bf16*)alloc((size_t)DIM * HIDDEN * 2);
    bf16* xbuf = (bf16*)alloc((size_t)SEQ * DIM * 2);
    bf16* qkv  = (bf16*)alloc((size_t)SEQ * QKVN * 2);
    float* h   = (float*)alloc((size_t)SEQ * DIM * 4);
    bf16* t1   = (bf16*)alloc((size_t)SEQ * HIDDEN * 2);
    float* Opart = (float*)alloc((size_t)NHEAD * NCHUNK_TOT * 64 * 128 * 4);
    float* Mpart = (float*)alloc((size_t)NHEAD * NCHUNK_TOT * 128 * 4);
    // split-K partials alias weight buffers dead by the W2 GEMM:
    // qkvt (24 MB, dead after QKV GEMM), w1t (23 MB, dead after gemm_w13).
    float* p0 = (float*)qkvt;   // 16.7 MB needed
    float* p1 = (float*)w1t;

    dim3 blk(256);

    cvt_t_kernel<<<dim3(DIM / 64, DIM / 64), blk, 0, stream>>>(wq, qkvt, DIM, DIM);
    cvt_t_kernel<<<dim3(DIM / 64, DIM / 64), blk, 0, stream>>>(wk, qkvt + (size_t)DIM * DIM, DIM, DIM);
    cvt_t_kernel<<<dim3(DIM / 64, DIM / 64), blk, 0, stream>>>(wv, qkvt + (size_t)2 * DIM * DIM, DIM, DIM);
    cvt_t_kernel<<<dim3(DIM / 64, DIM / 64), blk, 0, stream>>>(wo, wot, DIM, DIM);
    cvt_t_kernel<<<dim3(HIDDEN / 64, DIM / 64), blk, 0, stream>>>(w1, w1t, DIM, HIDDEN);
    cvt_t_kernel<<<dim3(HIDDEN / 64, DIM / 64), blk, 0, stream>>>(w3, w3t, DIM, HIDDEN);
    cvt_t_kernel<<<dim3(DIM / 64, HIDDEN / 64), blk, 0, stream>>>(w2, w2t, HIDDEN, DIM);

    rmsnorm_kernel<<<SEQ, blk, 0, stream>>>(x, g_attn, xbuf);
    gemm_qkv3<<<dim3(QKVN / 384, SEQ / 128), blk, 0, stream>>>(xbuf, qkvt, qkv, DIM, QKVN);
    rope_kernel<<<(SEQ * NHEAD * HD / 2) / 256, blk, 0, stream>>>(qkv, f_cos, f_sin);
    flash_attn_chunk<<<dim3(NCHUNK_TOT, NHEAD), blk, 0, stream>>>(qkv, Opart, Mpart);
    attn_combine<<<dim3(SEQ / 64, NHEAD), blk, 0, stream>>>(Opart, Mpart, xbuf);
    gemm_bf16<1><<<dim3(DIM / 128, SEQ / 128), blk, 0, stream>>>(xbuf, wot, h, x, DIM, DIM);
    rmsnorm_kernel<<<SEQ, blk, 0, stream>>>(h, g_ffn, xbuf);
    gemm_w13<<<dim3(HIDDEN / 128, SEQ / 128), blk, 0, stream>>>(xbuf, w1t, w3t, t1, DIM, HIDDEN);
    gemm_w2sk<<<dim3(DIM / 256, SEQ / 128, 2), blk, 0, stream>>>(t1, w2t, p0, p1, HIDDEN, HIDDEN / 2, DIM);
    combine2<<<dim3(SEQ * DIM / 1024), blk, 0, stream>>>(p0, p1, h, out);
}

// Round 7
// 730.105 us; speedup vs baseline: 1.1252x; 1.0473x over previous
//
#include <hip/hip_runtime.h>
#include <hip/hip_bf16.h>
#include <math.h>

#define SEQ 2048
#define DIM 2048
#define NHEAD 16
#define HD 128
#define HIDDEN 5632
#define QKVN 6144
#define NCHUNK_TOT 80   // sum_{it=0}^{31} (it/8 + 1)
constexpr float EPS = 1e-6f;

typedef __hip_bfloat16 bf16;
using short8  = __attribute__((ext_vector_type(8))) short;
using short4v = __attribute__((ext_vector_type(4))) short;
using floatx4 = __attribute__((ext_vector_type(4))) float;

__device__ inline void gl_lds16(const void* g, void* l) {
    __builtin_amdgcn_global_load_lds((const __attribute__((address_space(1))) void*)g,
                                     (__attribute__((address_space(3))) void*)l, 16, 0, 0);
}

__device__ inline short bfbits(float f) {
    bf16 b = __float2bfloat16(f);
    return *(const short*)&b;
}

// ---------------------------------------------------------------- rmsnorm (f32 in, bf16 out)
__global__ __launch_bounds__(256) void rmsnorm_kernel(const float* __restrict__ x,
                                                      const float* __restrict__ g,
                                                      bf16* __restrict__ out) {
    int row = blockIdx.x;
    const float4* xr = (const float4*)(x + (size_t)row * DIM);
    const float4* g4 = (const float4*)g;
    float4 v[2];
    float ss = 0.f;
#pragma unroll
    for (int i = 0; i < 2; ++i) {
        v[i] = xr[threadIdx.x + 256 * i];
        ss += v[i].x * v[i].x + v[i].y * v[i].y + v[i].z * v[i].z + v[i].w * v[i].w;
    }
    __shared__ float red[256];
    red[threadIdx.x] = ss;
    __syncthreads();
    for (int s = 128; s > 0; s >>= 1) {
        if (threadIdx.x < s) red[threadIdx.x] += red[threadIdx.x + s];
        __syncthreads();
    }
    float scale = rsqrtf(red[0] / (float)DIM + EPS);
    bf16* orow = out + (size_t)row * DIM;
#pragma unroll
    for (int i = 0; i < 2; ++i) {
        float4 gv = g4[threadIdx.x + 256 * i];
        short4v o;
        o[0] = bfbits(v[i].x * scale * gv.x);
        o[1] = bfbits(v[i].y * scale * gv.y);
        o[2] = bfbits(v[i].z * scale * gv.z);
        o[3] = bfbits(v[i].w * scale * gv.w);
        *(short4v*)&orow[(threadIdx.x + 256 * i) * 4] = o;
    }
}

// ---------------------------------------------------------------- weight cast+transpose
__global__ __launch_bounds__(256) void cvt_t_kernel(const float* __restrict__ in,
                                                    bf16* __restrict__ out,
                                                    int K, int N) {
    __shared__ bf16 L[64][72];
    const int nb = blockIdx.x * 64, kb = blockIdx.y * 64;
    const int t = threadIdx.x;
    const int nq = t & 15;   // n group of 4
    const int kq = t >> 4;   // k group of 4
    float4 v[4];
#pragma unroll
    for (int i = 0; i < 4; ++i)
        v[i] = *(const float4*)&in[(size_t)(kb + kq * 4 + i) * N + nb + nq * 4];
#pragma unroll
    for (int j = 0; j < 4; ++j) {
        short4v o;
#pragma unroll
        for (int i = 0; i < 4; ++i)
            o[i] = bfbits(((const float*)&v[i])[j]);
        *(short4v*)&L[nq * 4 + j][kq * 4] = o;
    }
    __syncthreads();
    const int c8 = t & 7, rw = t >> 3;
#pragma unroll
    for (int p = 0; p < 2; ++p) {
        int row = rw + p * 32;
        *(short8*)&out[(size_t)(nb + row) * K + kb + c8 * 8] = *(const short8*)&L[row][c8 * 8];
    }
}

// ---------------------------------------------------------------- bf16 MFMA GEMM (128x128, 2-phase)
template <int MODE>
__global__ __launch_bounds__(256) void gemm_bf16(const bf16* __restrict__ A,
                                                 const bf16* __restrict__ Bt,
                                                 void* __restrict__ Cv,
                                                 const float* __restrict__ R,
                                                 int K, int ldc) {
    __shared__ bf16 Asm[2][128 * 32];
    __shared__ bf16 Bsm[2][128 * 32];
    const int t = threadIdx.x;

    int wg = blockIdx.y * gridDim.x + blockIdx.x;
    {
        const int nwg = gridDim.x * gridDim.y;
        const int q = nwg >> 3, r = nwg & 7;
        const int xcd = wg & 7, loc = wg >> 3;
        wg = (xcd < r ? xcd * (q + 1) : r * (q + 1) + (xcd - r) * q) + loc;
    }
    const int m0 = (wg / gridDim.x) * 128;
    const int n0 = (wg % gridDim.x) * 128;

    const int lane = t & 63;
    const int wave = t >> 6;
    const int wr = wave >> 1, wc = wave & 1;
    const int quad = lane >> 4;
    const int l16 = lane & 15;

    floatx4 acc[4][4] = {};

    const int ar = t >> 2;
    const int ak = (t & 3) * 8;
    const bf16* Ag = A + (size_t)(m0 + ar) * K + ak;
    const bf16* Bg = Bt + (size_t)(n0 + ar) * K + ak;
    const size_t half = (size_t)64 * K;

    gl_lds16(Ag, Asm[0] + t * 8);
    gl_lds16(Ag + half, Asm[0] + t * 8 + 64 * 32);
    gl_lds16(Bg, Bsm[0] + t * 8);
    gl_lds16(Bg + half, Bsm[0] + t * 8 + 64 * 32);
    __syncthreads();

    int cur = 0;
    for (int k0 = 0; k0 < K; k0 += 32) {
        if (k0 + 32 < K) {
            const int nb = cur ^ 1;
            gl_lds16(Ag + k0 + 32, Asm[nb] + t * 8);
            gl_lds16(Ag + k0 + 32 + half, Asm[nb] + t * 8 + 64 * 32);
            gl_lds16(Bg + k0 + 32, Bsm[nb] + t * 8);
            gl_lds16(Bg + k0 + 32 + half, Bsm[nb] + t * 8 + 64 * 32);
        }

        const bf16* As = Asm[cur];
        const bf16* Bs = Bsm[cur];
        short8 af[4], bfr[4];
#pragma unroll
        for (int i = 0; i < 4; ++i)
            af[i] = *(const short8*)(As + (wr * 64 + i * 16 + l16) * 32 + quad * 8);
#pragma unroll
        for (int j = 0; j < 4; ++j)
            bfr[j] = *(const short8*)(Bs + (wc * 64 + j * 16 + l16) * 32 + quad * 8);
#pragma unroll
        for (int i = 0; i < 4; ++i)
#pragma unroll
            for (int j = 0; j < 4; ++j)
                acc[i][j] = __builtin_amdgcn_mfma_f32_16x16x32_bf16(af[i], bfr[j], acc[i][j], 0, 0, 0);

        __syncthreads();
        cur ^= 1;
    }

#pragma unroll
    for (int i = 0; i < 4; ++i) {
#pragma unroll
        for (int j = 0; j < 4; ++j) {
#pragma unroll
            for (int r = 0; r < 4; ++r) {
                int m = m0 + wr * 64 + i * 16 + quad * 4 + r;
                int n = n0 + wc * 64 + j * 16 + l16;
                size_t idx = (size_t)m * ldc + n;
                float v = acc[i][j][r];
                if (MODE == 0) {
                    ((bf16*)Cv)[idx] = __float2bfloat16(v);
                } else {
                    ((float*)Cv)[idx] = v + R[idx];
                }
            }
        }
    }
}

// ---------------------------------------------------------------- W2 wide split-K GEMM (128x256, K/2 per z)
// grid (8,16,2) = 512 blocks = 2/CU UNIFORM (uniform fill + >=2 blocks/CU:
// the round-5/6 lesson — wide-tile intensity needs both). blockIdx.z picks
// K-half and partial buffer. f32 partials; combine2 adds p0+p1+residual.
__global__ __launch_bounds__(256, 2) void gemm_w2sk(const bf16* __restrict__ A,
                                                    const bf16* __restrict__ Bt,
                                                    float* __restrict__ p0,
                                                    float* __restrict__ p1,
                                                    int ldk, int klen, int ldc) {
    __shared__ bf16 Asm[2][128 * 32];
    __shared__ bf16 B1s[2][128 * 32];
    __shared__ bf16 B3s[2][128 * 32];
    const int t = threadIdx.x;
    const int kbase = blockIdx.z * klen;
    float* outp = blockIdx.z ? p1 : p0;

    int wg = blockIdx.y * gridDim.x + blockIdx.x;
    {
        const int nwg = gridDim.x * gridDim.y;   // 128, div by 8 -> bijective
        const int q = nwg >> 3, r = nwg & 7;
        const int xcd = wg & 7, loc = wg >> 3;
        wg = (xcd < r ? xcd * (q + 1) : r * (q + 1) + (xcd - r) * q) + loc;
    }
    const int m0 = (wg / gridDim.x) * 128;
    const int n0 = (wg % gridDim.x) * 256;

    const int lane = t & 63;
    const int wave = t >> 6;
    const int wr = wave >> 1, wc = wave & 1;
    const int quad = lane >> 4;
    const int l16 = lane & 15;

    floatx4 acc1[4][4] = {};
    floatx4 acc3[4][4] = {};

    const int ar = t >> 2;
    const int ak = (t & 3) * 8;
    const bf16* Ag  = A  + (size_t)(m0 + ar) * ldk + kbase + ak;
    const bf16* B1g = Bt + (size_t)(n0 + ar) * ldk + kbase + ak;
    const bf16* B3g = Bt + (size_t)(n0 + 128 + ar) * ldk + kbase + ak;
    const size_t half = (size_t)64 * ldk;

    auto stage = [&](int k, int buf) {
        gl_lds16(Ag + k, Asm[buf] + t * 8);
        gl_lds16(Ag + k + half, Asm[buf] + t * 8 + 64 * 32);
        gl_lds16(B1g + k, B1s[buf] + t * 8);
        gl_lds16(B1g + k + half, B1s[buf] + t * 8 + 64 * 32);
        gl_lds16(B3g + k, B3s[buf] + t * 8);
        gl_lds16(B3g + k + half, B3s[buf] + t * 8 + 64 * 32);
    };

    stage(0, 0);
    __syncthreads();

    int cur = 0;
    for (int k0 = 0; k0 < klen; k0 += 32) {
        if (k0 + 32 < klen) stage(k0 + 32, cur ^ 1);

        const bf16* As = Asm[cur];
        short8 af[4], bfr[4];
#pragma unroll
        for (int i = 0; i < 4; ++i)
            af[i] = *(const short8*)(As + (wr * 64 + i * 16 + l16) * 32 + quad * 8);

        const bf16* B1 = B1s[cur];
#pragma unroll
        for (int j = 0; j < 4; ++j)
            bfr[j] = *(const short8*)(B1 + (wc * 64 + j * 16 + l16) * 32 + quad * 8);
#pragma unroll
        for (int i = 0; i < 4; ++i)
#pragma unroll
            for (int j = 0; j < 4; ++j)
                acc1[i][j] = __builtin_amdgcn_mfma_f32_16x16x32_bf16(af[i], bfr[j], acc1[i][j], 0, 0, 0);

        const bf16* B3 = B3s[cur];
#pragma unroll
        for (int j = 0; j < 4; ++j)
            bfr[j] = *(const short8*)(B3 + (wc * 64 + j * 16 + l16) * 32 + quad * 8);
#pragma unroll
        for (int i = 0; i < 4; ++i)
#pragma unroll
            for (int j = 0; j < 4; ++j)
                acc3[i][j] = __builtin_amdgcn_mfma_f32_16x16x32_bf16(af[i], bfr[j], acc3[i][j], 0, 0, 0);

        __syncthreads();
        cur ^= 1;
    }

#pragma unroll
    for (int i = 0; i < 4; ++i)
#pragma unroll
        for (int j = 0; j < 4; ++j)
#pragma unroll
            for (int r = 0; r < 4; ++r) {
                int m = m0 + wr * 64 + i * 16 + quad * 4 + r;
                int n = n0 + wc * 64 + j * 16 + l16;
                outp[(size_t)m * ldc + n]       = acc1[i][j][r];
                outp[(size_t)m * ldc + n + 128] = acc3[i][j][r];
            }
}

// ---------------------------------------------------------------- fused W1/W3 SwiGLU GEMM
__global__ __launch_bounds__(256, 2) void gemm_w13(const bf16* __restrict__ A,
                                                   const bf16* __restrict__ B1t,
                                                   const bf16* __restrict__ B3t,
                                                   bf16* __restrict__ C,
                                                   int K, int ldc) {
    __shared__ bf16 Asm[2][128 * 32];
    __shared__ bf16 B1s[2][128 * 32];
    __shared__ bf16 B3s[2][128 * 32];
    const int t = threadIdx.x;

    int wg = blockIdx.y * gridDim.x + blockIdx.x;
    {
        const int nwg = gridDim.x * gridDim.y;
        const int q = nwg >> 3, r = nwg & 7;
        const int xcd = wg & 7, loc = wg >> 3;
        wg = (xcd < r ? xcd * (q + 1) : r * (q + 1) + (xcd - r) * q) + loc;
    }
    const int m0 = (wg / gridDim.x) * 128;
    const int n0 = (wg % gridDim.x) * 128;

    const int lane = t & 63;
    const int wave = t >> 6;
    const int wr = wave >> 1, wc = wave & 1;
    const int quad = lane >> 4;
    const int l16 = lane & 15;

    floatx4 acc1[4][4] = {};
    floatx4 acc3[4][4] = {};

    const int ar = t >> 2;
    const int ak = (t & 3) * 8;
    const bf16* Ag  = A   + (size_t)(m0 + ar) * K + ak;
    const bf16* B1g = B1t + (size_t)(n0 + ar) * K + ak;
    const bf16* B3g = B3t + (size_t)(n0 + ar) * K + ak;
    const size_t half = (size_t)64 * K;

    auto stage = [&](int k, int buf) {
        gl_lds16(Ag + k, Asm[buf] + t * 8);
        gl_lds16(Ag + k + half, Asm[buf] + t * 8 + 64 * 32);
        gl_lds16(B1g + k, B1s[buf] + t * 8);
        gl_lds16(B1g + k + half, B1s[buf] + t * 8 + 64 * 32);
        gl_lds16(B3g + k, B3s[buf] + t * 8);
        gl_lds16(B3g + k + half, B3s[buf] + t * 8 + 64 * 32);
    };

    stage(0, 0);
    __syncthreads();

    int cur = 0;
    for (int k0 = 0; k0 < K; k0 += 32) {
        if (k0 + 32 < K) stage(k0 + 32, cur ^ 1);

        const bf16* As = Asm[cur];
        short8 af[4], bfr[4];
#pragma unroll
        for (int i = 0; i < 4; ++i)
            af[i] = *(const short8*)(As + (wr * 64 + i * 16 + l16) * 32 + quad * 8);

        const bf16* B1 = B1s[cur];
#pragma unroll
        for (int j = 0; j < 4; ++j)
            bfr[j] = *(const short8*)(B1 + (wc * 64 + j * 16 + l16) * 32 + quad * 8);
#pragma unroll
        for (int i = 0; i < 4; ++i)
#pragma unroll
            for (int j = 0; j < 4; ++j)
                acc1[i][j] = __builtin_amdgcn_mfma_f32_16x16x32_bf16(af[i], bfr[j], acc1[i][j], 0, 0, 0);

        const bf16* B3 = B3s[cur];
#pragma unroll
        for (int j = 0; j < 4; ++j)
            bfr[j] = *(const short8*)(B3 + (wc * 64 + j * 16 + l16) * 32 + quad * 8);
#pragma unroll
        for (int i = 0; i < 4; ++i)
#pragma unroll
            for (int j = 0; j < 4; ++j)
                acc3[i][j] = __builtin_amdgcn_mfma_f32_16x16x32_bf16(af[i], bfr[j], acc3[i][j], 0, 0, 0);

        __syncthreads();
        cur ^= 1;
    }

#pragma unroll
    for (int i = 0; i < 4; ++i) {
#pragma unroll
        for (int j = 0; j < 4; ++j) {
#pragma unroll
            for (int r = 0; r < 4; ++r) {
                int m = m0 + wr * 64 + i * 16 + quad * 4 + r;
                int n = n0 + wc * 64 + j * 16 + l16;
                float v1 = acc1[i][j][r];
                float v3 = acc3[i][j][r];
                float s = v1 / (1.f + __expf(-v1));
                C[(size_t)m * ldc + n] = __float2bfloat16(s * v3);
            }
        }
    }
}

// ---------------------------------------------------------------- split-K combine: out = p0+p1+h
__global__ __launch_bounds__(256) void combine2(const float* __restrict__ p0,
                                                const float* __restrict__ p1,
                                                const float* __restrict__ h,
                                                float* __restrict__ out) {
    size_t i = ((size_t)blockIdx.x * 256 + threadIdx.x) * 4;
    float4 a = *(const float4*)&p0[i];
    float4 b = *(const float4*)&p1[i];
    float4 c = *(const float4*)&h[i];
    float4 o;
    o.x = a.x + b.x + c.x;
    o.y = a.y + b.y + c.y;
    o.z = a.z + b.z + c.z;
    o.w = a.w + b.w + c.w;
    *(float4*)&out[i] = o;
}

// ---------------------------------------------------------------- RoPE (in-place, bf16 qkv buffer)
__global__ __launch_bounds__(256) void rope_kernel(bf16* __restrict__ qkv,
                                                   const float* __restrict__ cs,
                                                   const float* __restrict__ sn) {
    int idx = blockIdx.x * 256 + threadIdx.x;
    int d2 = idx % (HD / 2);
    int rest = idx / (HD / 2);
    int h = rest % NHEAD;
    int s = rest / NHEAD;
    float c = cs[s * (HD / 2) + d2];
    float si = sn[s * (HD / 2) + d2];
    bf16* qp = qkv + (size_t)s * QKVN + h * HD + 2 * d2;
    bf16* kp = qp + DIM;
    float qr = __bfloat162float(qp[0]), qi = __bfloat162float(qp[1]);
    qp[0] = __float2bfloat16(qr * c - qi * si);
    qp[1] = __float2bfloat16(qr * si + qi * c);
    float kr = __bfloat162float(kp[0]), ki = __bfloat162float(kp[1]);
    kp[0] = __float2bfloat16(kr * c - ki * si);
    kp[1] = __float2bfloat16(kr * si + ki * c);
}

// ---------------------------------------------------------------- chunked MFMA flash attention
__global__ __launch_bounds__(256, 3) void flash_attn_chunk(const bf16* __restrict__ qkv,
                                                           float* __restrict__ Opart,
                                                           float* __restrict__ Mpart) {
    __shared__ bf16 Ks[64][136];    // key-major, pad 8 (stride 272 B)
    __shared__ bf16 Vt[128][72];    // dim-major, pad 8 (stride 144 B)
    __shared__ bf16 Ps[64][72];

    const int h = blockIdx.y;
    int rem = blockIdx.x, it = 0;
    for (;;) { int nc = (it >> 3) + 1; if (rem < nc) break; rem -= nc; ++it; }
    const int c = rem;
    const int q8 = it >> 3, r8 = it & 7;
    const int slot = h * NCHUNK_TOT + (q8 + 1) * (4 * q8 + r8) + c;
    const int j0 = c * 8;
    const int j1 = (j0 + 8 < it + 1) ? (j0 + 8) : (it + 1);

    const int t = threadIdx.x;
    const int lane = t & 63;
    const int w = t >> 6;
    const int quad = lane >> 4;
    const int l16 = lane & 15;
    const int s0 = it * 64;
    const float sl2 = (float)(0.08838834764831845 * 1.4426950408889634);

    short8 qreg[4];
    {
        const bf16* qrow = qkv + (size_t)(s0 + 16 * w + l16) * QKVN + h * HD + quad * 8;
#pragma unroll
        for (int ks = 0; ks < 4; ++ks)
            qreg[ks] = *(const short8*)(qrow + ks * 32);
    }

    floatx4 O[8] = {};
    float m_i[4], l_i[4];
#pragma unroll
    for (int r = 0; r < 4; ++r) { m_i[r] = -INFINITY; l_i[r] = 0.f; }

    const int vkg = t >> 5;
    const int vdg = t & 31;

    for (int jt = j0; jt < j1; ++jt) {
        const int tb = jt * 64;
        __syncthreads();

#pragma unroll
        for (int u = 0; u < 4; ++u) {
            int vv = t + 256 * u;
            int kr = vv >> 4, kc = vv & 15;
            *(uint4*)&Ks[kr][kc * 8] =
                *(const uint4*)(qkv + (size_t)(tb + kr) * QKVN + DIM + h * HD + kc * 8);
        }
        {
            short4v vr[8];
#pragma unroll
            for (int kk = 0; kk < 8; ++kk)
                vr[kk] = *(const short4v*)(qkv + (size_t)(tb + vkg * 8 + kk) * QKVN + 2 * DIM + h * HD + vdg * 4);
#pragma unroll
            for (int dd = 0; dd < 4; ++dd) {
                short8 wv;
#pragma unroll
                for (int kk = 0; kk < 8; ++kk) wv[kk] = vr[kk][dd];
                *(short8*)&Vt[vdg * 4 + dd][vkg * 8] = wv;
            }
        }
        __syncthreads();

        floatx4 sacc[4] = {};
#pragma unroll
        for (int ks = 0; ks < 4; ++ks) {
            short8 kb[4];
#pragma unroll
            for (int nt = 0; nt < 4; ++nt)
                kb[nt] = *(const short8*)&Ks[nt * 16 + l16][ks * 32 + quad * 8];
#pragma unroll
            for (int nt = 0; nt < 4; ++nt)
                sacc[nt] = __builtin_amdgcn_mfma_f32_16x16x32_bf16(qreg[ks], kb[nt], sacc[nt], 0, 0, 0);
        }

        float alpha[4];
#pragma unroll
        for (int r = 0; r < 4; ++r) {
            float mx = -INFINITY;
#pragma unroll
            for (int nt = 0; nt < 4; ++nt) {
                float s = sacc[nt][r] * sl2;
                if (jt == it && (nt * 16 + l16) > (16 * w + quad * 4 + r)) s = -INFINITY;
                sacc[nt][r] = s;
                mx = fmaxf(mx, s);
            }
#pragma unroll
            for (int off = 1; off < 16; off <<= 1)
                mx = fmaxf(mx, __shfl_xor(mx, off, 64));
            float mn = fmaxf(m_i[r], mx);
            alpha[r] = exp2f(m_i[r] - mn);
            float lsum = 0.f;
#pragma unroll
            for (int nt = 0; nt < 4; ++nt) {
                float e = exp2f(sacc[nt][r] - mn);
                sacc[nt][r] = e;
                lsum += e;
            }
#pragma unroll
            for (int off = 1; off < 16; off <<= 1)
                lsum += __shfl_xor(lsum, off, 64);
            l_i[r] = l_i[r] * alpha[r] + lsum;
            m_i[r] = mn;
        }

#pragma unroll
        for (int nt = 0; nt < 4; ++nt)
#pragma unroll
            for (int r = 0; r < 4; ++r)
                Ps[16 * w + quad * 4 + r][nt * 16 + l16] = __float2bfloat16(sacc[nt][r]);

#pragma unroll
        for (int nt = 0; nt < 8; ++nt)
#pragma unroll
            for (int r = 0; r < 4; ++r)
                O[nt][r] *= alpha[r];

#pragma unroll
        for (int ks = 0; ks < 2; ++ks) {
            short8 pa = *(const short8*)&Ps[16 * w + l16][ks * 32 + quad * 8];
#pragma unroll
            for (int nt = 0; nt < 8; ++nt) {
                short8 vb = *(const short8*)&Vt[nt * 16 + l16][ks * 32 + quad * 8];
                O[nt] = __builtin_amdgcn_mfma_f32_16x16x32_bf16(pa, vb, O[nt], 0, 0, 0);
            }
        }
    }

    float* Op = Opart + (size_t)slot * (64 * 128);
    float* Mp = Mpart + (size_t)slot * 128;
    if (l16 == 0) {
#pragma unroll
        for (int r = 0; r < 4; ++r) {
            int row = 16 * w + quad * 4 + r;
            Mp[row] = m_i[r];
            Mp[64 + row] = l_i[r];
        }
    }
#pragma unroll
    for (int r = 0; r < 4; ++r) {
        int row = 16 * w + quad * 4 + r;
#pragma unroll
        for (int nt = 0; nt < 8; ++nt)
            Op[row * 128 + nt * 16 + l16] = O[nt][r];
    }
}

// ---------------------------------------------------------------- combine partials -> bf16 out
__global__ __launch_bounds__(256) void attn_combine(const float* __restrict__ Opart,
                                                    const float* __restrict__ Mpart,
                                                    bf16* __restrict__ out) {
    const int it = blockIdx.x;
    const int h = blockIdx.y;
    const int nch = (it >> 3) + 1;
    const int q8 = it >> 3, r8 = it & 7;
    const int base = h * NCHUNK_TOT + (q8 + 1) * (4 * q8 + r8);
    const int t = threadIdx.x;
    const int row = t >> 2;
    const int dq = t & 3;

    float mv[4], wgt[4];
    float M = -INFINITY;
#pragma unroll
    for (int c = 0; c < 4; ++c) {
        if (c < nch) {
            mv[c] = Mpart[(size_t)(base + c) * 128 + row];
            M = fmaxf(M, mv[c]);
        }
    }
    float L = 0.f;
#pragma unroll
    for (int c = 0; c < 4; ++c) {
        if (c < nch) {
            wgt[c] = exp2f(mv[c] - M);
            L += Mpart[(size_t)(base + c) * 128 + 64 + row] * wgt[c];
        }
    }
    float inv = 1.f / L;

    float acc[32] = {};
#pragma unroll
    for (int c = 0; c < 4; ++c) {
        if (c < nch) {
            const float* Oc = Opart + ((size_t)(base + c) * 64 + row) * 128 + dq * 32;
            float wc = wgt[c];
#pragma unroll
            for (int k = 0; k < 8; ++k) {
                float4 v = *(const float4*)&Oc[k * 4];
                acc[k * 4 + 0] += wc * v.x;
                acc[k * 4 + 1] += wc * v.y;
                acc[k * 4 + 2] += wc * v.z;
                acc[k * 4 + 3] += wc * v.w;
            }
        }
    }

    bf16* orow = out + (size_t)(it * 64 + row) * DIM + h * HD + dq * 32;
#pragma unroll
    for (int k2 = 0; k2 < 4; ++k2) {
        short8 pk;
#pragma unroll
        for (int e = 0; e < 8; ++e)
            pk[e] = bfbits(acc[k2 * 8 + e] * inv);
        *(short8*)&orow[k2 * 8] = pk;
    }
}

// ---------------------------------------------------------------- launch
extern "C" void kernel_launch(void* const* d_in, const int* in_sizes, int n_in,
                              void* d_out, int out_size, void* d_ws, size_t ws_size,
                              hipStream_t stream) {
    const float* x      = (const float*)d_in[0];
    const float* f_cos  = (const float*)d_in[1];
    const float* f_sin  = (const float*)d_in[2];
    // d_in[3] = mask : ignored (causality analytic)
    const float* wq     = (const float*)d_in[4];
    const float* wk     = (const float*)d_in[5];
    const float* wv     = (const float*)d_in[6];
    const float* wo     = (const float*)d_in[7];
    const float* w1     = (const float*)d_in[8];
    const float* w2     = (const float*)d_in[9];
    const float* w3     = (const float*)d_in[10];
    const float* g_attn = (const float*)d_in[11];
    const float* g_ffn  = (const float*)d_in[12];
    float* out = (float*)d_out;

    char* base = (char*)d_ws;
    size_t off = 0;
    auto alloc = [&](size_t bytes) { void* p = base + off; off += (bytes + 255) & ~255ULL; return p; };
    bf16* qkvt = (bf16*)alloc((size_t)QKVN * DIM * 2);
    bf16* wot  = (bf16*)alloc((size_t)DIM * DIM * 2);
    bf16* w1t  = (bf16*)alloc((size_t)HIDDEN * DIM * 2);
    bf16* w3t  = (bf16*)alloc((size_t)HIDDEN * DIM * 2);
    bf16* w2t  = (bf16*)alloc((size_t)DIM * HIDDEN * 2);
    bf16* xbuf = (bf16*)alloc((size_t)SEQ * DIM * 2);
    bf16* qkv  = (bf16*)alloc((size_t)SEQ * QKVN * 2);
    float* h   = (float*)alloc((size_t)SEQ * DIM * 4);
    bf16* t1   = (bf16*)alloc((size_t)SEQ * HIDDEN * 2);
    float* Opart = (float*)alloc((size_t)NHEAD * NCHUNK_TOT * 64 * 128 * 4);
    float* Mpart = (float*)alloc((size_t)NHEAD * NCHUNK_TOT * 128 * 4);
    // split-K partials alias weight buffers dead by the W2 GEMM:
    // qkvt (24 MB, dead after QKV GEMM), w1t (23 MB, dead after gemm_w13).
    float* p0 = (float*)qkvt;   // 16.7 MB needed
    float* p1 = (float*)w1t;

    dim3 blk(256);

    cvt_t_kernel<<<dim3(DIM / 64, DIM / 64), blk, 0, stream>>>(wq, qkvt, DIM, DIM);
    cvt_t_kernel<<<dim3(DIM / 64, DIM / 64), blk, 0, stream>>>(wk, qkvt + (size_t)DIM * DIM, DIM, DIM);
    cvt_t_kernel<<<dim3(DIM / 64, DIM / 64), blk, 0, stream>>>(wv, qkvt + (size_t)2 * DIM * DIM, DIM, DIM);
    cvt_t_kernel<<<dim3(DIM / 64, DIM / 64), blk, 0, stream>>>(wo, wot, DIM, DIM);
    cvt_t_kernel<<<dim3(HIDDEN / 64, DIM / 64), blk, 0, stream>>>(w1, w1t, DIM, HIDDEN);
    cvt_t_kernel<<<dim3(HIDDEN / 64, DIM / 64), blk, 0, stream>>>(w3, w3t, DIM, HIDDEN);
    cvt_t_kernel<<<dim3(DIM / 64, HIDDEN / 64), blk, 0, stream>>>(w2, w2t, HIDDEN, DIM);

    rmsnorm_kernel<<<SEQ, blk, 0, stream>>>(x, g_attn, xbuf);
    gemm_bf16<0><<<dim3(QKVN / 128, SEQ / 128), blk, 0, stream>>>(xbuf, qkvt, qkv, nullptr, DIM, QKVN);
    rope_kernel<<<(SEQ * NHEAD * HD / 2) / 256, blk, 0, stream>>>(qkv, f_cos, f_sin);
    flash_attn_chunk<<<dim3(NCHUNK_TOT, NHEAD), blk, 0, stream>>>(qkv, Opart, Mpart);
    attn_combine<<<dim3(SEQ / 64, NHEAD), blk, 0, stream>>>(Opart, Mpart, xbuf);
    gemm_bf16<1><<<dim3(DIM / 128, SEQ / 128), blk, 0, stream>>>(xbuf, wot, h, x, DIM, DIM);
    rmsnorm_kernel<<<SEQ, blk, 0, stream>>>(h, g_ffn, xbuf);
    gemm_w13<<<dim3(HIDDEN / 128, SEQ / 128), blk, 0, stream>>>(xbuf, w1t, w3t, t1, DIM, HIDDEN);
    gemm_w2sk<<<dim3(DIM / 256, SEQ / 128, 2), blk, 0, stream>>>(t1, w2t, p0, p1, HIDDEN, HIDDEN / 2, DIM);
    combine2<<<dim3(SEQ * DIM / 1024), blk, 0, stream>>>(p0, p1, h, out);
}